// Round 10
// baseline (237.710 us; speedup 1.0000x reference)
//
#include <hip/hip_runtime.h>
#include <math.h>

#define NF 147
#define NBLK 224

__device__ __forceinline__ void gbar(int* cnt, int target) {
    __syncthreads();
    __threadfence();                        // release: drain + L2 writeback
    if (threadIdx.x == 0) {
        atomicAdd(cnt, 1);
        while (atomicAdd(cnt, 0) < target) { }
    }
    __syncthreads();                        // wait for arrival of all blocks
    __threadfence();                        // acquire: invalidate stale lines
}

// ---------------------------------------------------------------------------
// kF: single persistent kernel, 224 blocks x 256 threads, wide phases.
//  P1: blk 0..127  h1 = silu(e @ t_w1 + t_b1)        (32 b x 4 j-quarters)
//      blk 128..210 WM = concat(t_w2|pfc_w|pe_w|pe_b+pfc_b|t_b2) @ o_w1
//                  (8 rows/blk, LDS-staged src, float4, 4-way k-split)
//  -- barrier A (224) --
//  P2: blk 0..159  geometry + nerf -> g1[s][c] (k=151 over WM rows 512..662)
//      blk 160..223 tg[b][ch] = h1[b,:]·WM[0:512,c] + WM[663,c] + o_b1[c]
//  -- barrier B (224); blocks >=80 exit --
//  P3: blk 0..79   rows=g1+tg; stats1 | C(80) | bn1+relu+fc2; stats2 | D(80) |
//                  bn2+relu+fc3 -> out
// ---------------------------------------------------------------------------
__global__ __launch_bounds__(256) void kF(
    const float* __restrict__ noise, const int* __restrict__ tsteps,
    const float* __restrict__ pcs, const int* __restrict__ bl,
    const float* __restrict__ pe_w, const float* __restrict__ pe_b,
    const float* __restrict__ t_w1, const float* __restrict__ t_b1,
    const float* __restrict__ t_w2, const float* __restrict__ t_b2,
    const float* __restrict__ pfc_w, const float* __restrict__ pfc_b,
    const float* __restrict__ o_w1, const float* __restrict__ o_b1,
    const float* __restrict__ bn1_g, const float* __restrict__ bn1_b,
    const float* __restrict__ o_w2, const float* __restrict__ o_b2,
    const float* __restrict__ bn2_g, const float* __restrict__ bn2_b,
    const float* __restrict__ o_w3, const float* __restrict__ o_b3,
    float* __restrict__ h1, float* __restrict__ WM,
    float* __restrict__ g1, float* __restrict__ tg,
    float* __restrict__ stats1, float* __restrict__ stats2,
    int* __restrict__ cnts, float* __restrict__ out)
{
    __shared__ float shm[12288];   // 48 KB, reused per phase
    __shared__ float np7s[4][8];
    __shared__ float wsum[4][3];
    __shared__ float rms[4][3];
    int blk = blockIdx.x, tid = threadIdx.x;

    // ======================= phase 1 =======================
    if (blk < 128) {
        int b = blk >> 2, jq = blk & 3;
        float tf = (float)tsteps[b];
        float f = expf(-9.210340371976184f * (float)tid * (1.f / 256.f));
        float sn, cs;
        sincosf(tf * f, &sn, &cs);
        shm[tid] = cs; shm[256 + tid] = sn;       // e[512]
        __syncthreads();
        int jj = tid & 127, j = jq * 128 + jj;
        int ks = tid >> 7, k0 = ks << 8;
        float acc = 0.f;
        #pragma unroll 8
        for (int k = k0; k < k0 + 256; k++) acc += shm[k] * t_w1[k * 512 + j];
        shm[512 + ks * 128 + jj] = acc;
        __syncthreads();
        if (tid < 128) {
            float v = shm[512 + tid] + shm[640 + tid] + t_b1[jq * 128 + tid];
            h1[b * 512 + jq * 128 + tid] = v / (1.f + expf(-v));
        }
    } else if (blk < 211) {
        int m = blk - 128, r8 = m * 8;
        float* srcs = shm;          // [8][512]
        float* red  = shm + 4096;   // [4][8][256]
        #pragma unroll
        for (int q = 0; q < 4; q++) {
            int idx = tid + q * 256;
            int row = idx >> 7;
            int off4 = (idx & 127) << 2;
            int kr = r8 + row;
            float4 v;
            if (kr < 512)      v = *(const float4*)&t_w2[(size_t)kr * 512 + off4];
            else if (kr < 659) v = *(const float4*)&pfc_w[(size_t)(kr - 512) * 512 + off4];
            else if (kr < 662) v = *(const float4*)&pe_w[(size_t)(kr - 659) * 512 + off4];
            else if (kr == 662) {
                float4 a = *(const float4*)&pe_b[off4];
                float4 bq = *(const float4*)&pfc_b[off4];
                v.x = a.x + bq.x; v.y = a.y + bq.y; v.z = a.z + bq.z; v.w = a.w + bq.w;
            } else v = *(const float4*)&t_b2[off4];
            *(float4*)&srcs[row * 512 + off4] = v;
        }
        __syncthreads();
        int ks = tid >> 6, c4 = (tid & 63) << 2;
        float4 acc[8];
        #pragma unroll
        for (int i = 0; i < 8; i++) acc[i] = make_float4(0.f, 0.f, 0.f, 0.f);
        int j0 = ks * 128;
        #pragma unroll 4
        for (int jj = 0; jj < 128; jj++) {
            int j = j0 + jj;
            float4 w = *(const float4*)&o_w1[j * 256 + c4];
            #pragma unroll
            for (int i = 0; i < 8; i++) {
                float s = srcs[i * 512 + j];
                acc[i].x += s * w.x; acc[i].y += s * w.y;
                acc[i].z += s * w.z; acc[i].w += s * w.w;
            }
        }
        #pragma unroll
        for (int i = 0; i < 8; i++) *(float4*)&red[(ks * 8 + i) * 256 + c4] = acc[i];
        __syncthreads();
        #pragma unroll
        for (int t = 0; t < 8; t++) {
            int o = tid + t * 256;
            int i = o >> 8, c = o & 255;
            WM[(size_t)(r8 + i) * 256 + c] = red[i * 256 + c] + red[(8 + i) * 256 + c]
                                           + red[(16 + i) * 256 + c] + red[(24 + i) * 256 + c];
        }
    }
    // blocks 211..223 idle in phase 1

    gbar(&cnts[0], NBLK);

    // ======================= phase 2 =======================
    if (blk < 160) {
        int s0 = blk * 4;
        {
            const float4* p4 = (const float4*)(pcs + (size_t)blk * 3000);
            #pragma unroll
            for (int i = 0; i < 3; i++) {
                int idx = tid + i * 256;
                if (idx < 750) *(float4*)&shm[idx * 4] = p4[idx];
            }
        }
        if (tid < 28) np7s[tid / 7][tid % 7] = noise[s0 * 7 + tid];
        __syncthreads();
        int w = tid >> 6, lane = tid & 63;
        {
            float sx = 0.f, sy = 0.f, sz = 0.f;
            const float* base = shm + w * 750;
            #pragma unroll
            for (int it = 0; it < 4; it++) {
                int q = lane + it * 64;
                if (q < 250) {
                    sx += base[q * 3 + 0];
                    sy += base[q * 3 + 1];
                    sz += base[q * 3 + 2];
                }
            }
            for (int off = 32; off >= 1; off >>= 1) {
                sx += __shfl_down(sx, off, 64);
                sy += __shfl_down(sy, off, 64);
                sz += __shfl_down(sz, off, 64);
            }
            if (lane == 0) { wsum[w][0] = sx; wsum[w][1] = sy; wsum[w][2] = sz; }
        }
        __syncthreads();
        if (tid < 4) {
            float inv = 1.f / (float)bl[s0 + tid];
            float mx = wsum[tid][0] * inv, my = wsum[tid][1] * inv, mz = wsum[tid][2] * inv;
            float qw = np7s[tid][3], qx = np7s[tid][4], qy = np7s[tid][5], qz = np7s[tid][6];
            float qn = rsqrtf(qw * qw + qx * qx + qy * qy + qz * qz);
            qw *= qn; qx *= qn; qy *= qn; qz *= qn;
            float tx = 2.f * (qy * mz - qz * my);
            float ty = 2.f * (qz * mx - qx * mz);
            float tz = 2.f * (qx * my - qy * mx);
            rms[tid][0] = mx + qw * tx + (qy * tz - qz * ty) + np7s[tid][0];
            rms[tid][1] = my + qw * ty + (qz * tx - qx * tz) + np7s[tid][1];
            rms[tid][2] = mz + qw * tz + (qx * ty - qy * tx) + np7s[tid][2];
        }
        for (int u = tid; u < 4 * NF; u += 256) {
            int r = u / NF, f = u % NF;
            float v;
            if (f < 7) v = np7s[r][f];
            else {
                int j = f - 7;
                int fi = j / 14, x = j % 14;
                float band = (float)(1 << fi);
                v = (x < 7) ? sinf(np7s[r][x] * band) : cosf(np7s[r][x - 7] * band);
            }
            shm[3008 + r * 148 + f] = v;
        }
        __syncthreads();
        int c = tid;
        float b0 = WM[662 * 256 + c];
        float a0 = b0, a1 = b0, a2 = b0, a3 = b0;
        #pragma unroll 7
        for (int f = 0; f < NF; f++) {
            float wv = WM[(512 + f) * 256 + c];
            a0 += shm[3008 + f] * wv;
            a1 += shm[3008 + 148 + f] * wv;
            a2 += shm[3008 + 296 + f] * wv;
            a3 += shm[3008 + 444 + f] * wv;
        }
        #pragma unroll
        for (int d = 0; d < 3; d++) {
            float wv = WM[(659 + d) * 256 + c];
            a0 += rms[0][d] * wv;
            a1 += rms[1][d] * wv;
            a2 += rms[2][d] * wv;
            a3 += rms[3][d] * wv;
        }
        g1[(s0 + 0) * 256 + c] = a0;
        g1[(s0 + 1) * 256 + c] = a1;
        g1[(s0 + 2) * 256 + c] = a2;
        g1[(s0 + 3) * 256 + c] = a3;
    } else {
        int q = blk - 160;
        int b = q >> 1, ch = q & 1;
        shm[tid] = h1[b * 512 + tid];
        shm[256 + tid] = h1[b * 512 + 256 + tid];
        __syncthreads();
        int cc = tid & 127, c = ch * 128 + cc;
        int ks = tid >> 7, k0 = ks << 8;
        float acc = 0.f;
        #pragma unroll 8
        for (int k = k0; k < k0 + 256; k++) acc += shm[k] * WM[k * 256 + c];
        shm[512 + ks * 128 + cc] = acc;
        __syncthreads();
        if (tid < 128) {
            int c2 = ch * 128 + tid;
            tg[b * 256 + c2] = shm[512 + tid] + shm[640 + tid] + WM[663 * 256 + c2] + o_b1[c2];
        }
    }

    gbar(&cnts[1], NBLK);

    if (blk >= 80) return;

    // ======================= phase 3 (80 blocks) =======================
    int r0 = blk * 8;
    float* rows  = shm;           // 2048
    float* scale = shm + 2048;    // 256
    float* shift = shm + 2304;    // 256
    float* rowsB = shm + 2560;    // 1024
    float* w3s   = shm + 3584;    // 896
    float* red2  = shm + 4608;    // [2][8][128] = 2048

    #pragma unroll
    for (int w = 0; w < 2; w++) {
        int i4 = tid + w * 256;               // 0..511 float4 units
        int r = i4 >> 6, c = (i4 & 63) << 2;
        float4 gv = *(const float4*)&g1[(size_t)(r0 + r) * 256 + c];
        float4 tv = *(const float4*)&tg[(size_t)((r0 + r) / 20) * 256 + c];
        gv.x += tv.x; gv.y += tv.y; gv.z += tv.z; gv.w += tv.w;
        *(float4*)&rows[r * 256 + c] = gv;
    }
    for (int i = tid; i < 896; i += 256) w3s[i] = o_w3[i];
    __syncthreads();
    {
        float sm = 0.f, ss = 0.f;
        #pragma unroll
        for (int r = 0; r < 8; r++) { float x = rows[r * 256 + tid]; sm += x; ss += x * x; }
        atomicAdd(&stats1[tid], sm);
        atomicAdd(&stats1[256 + tid], ss);
    }

    gbar(&cnts[2], 80);

    {
        float m = stats1[tid] * (1.f / 640.f);
        float v = stats1[256 + tid] * (1.f / 640.f) - m * m;
        float sc = rsqrtf(v + 1e-5f) * bn1_g[tid];
        scale[tid] = sc;
        shift[tid] = bn1_b[tid] - m * sc;
    }
    __syncthreads();
    for (int i = tid; i < 2048; i += 256) {
        int r = i >> 8, c = i & 255;
        float x = rows[r * 256 + c] * scale[c] + shift[c];
        rows[r * 256 + c] = x > 0.f ? x : 0.f;
    }
    __syncthreads();
    {
        int ks = tid >> 7, c2 = tid & 127;
        float acc[8];
        #pragma unroll
        for (int r = 0; r < 8; r++) acc[r] = 0.f;
        int kb = ks * 128;
        #pragma unroll 8
        for (int kk = 0; kk < 128; kk++) {
            int k = kb + kk;
            float w = o_w2[k * 128 + c2];
            #pragma unroll
            for (int r = 0; r < 8; r++) acc[r] += rows[r * 256 + k] * w;
        }
        #pragma unroll
        for (int r = 0; r < 8; r++) red2[(ks * 8 + r) * 128 + c2] = acc[r];
    }
    __syncthreads();
    if (tid < 128) {
        float bb = o_b2[tid];
        float sm = 0.f, ss = 0.f;
        #pragma unroll
        for (int r = 0; r < 8; r++) {
            float h = red2[r * 128 + tid] + red2[(8 + r) * 128 + tid] + bb;
            rowsB[r * 128 + tid] = h;
            sm += h; ss += h * h;
        }
        atomicAdd(&stats2[tid], sm);
        atomicAdd(&stats2[128 + tid], ss);
    }

    gbar(&cnts[3], 80);

    if (tid < 128) {
        float m = stats2[tid] * (1.f / 640.f);
        float v = stats2[128 + tid] * (1.f / 640.f) - m * m;
        float sc = rsqrtf(v + 1e-5f) * bn2_g[tid];
        float sh = bn2_b[tid] - m * sc;
        #pragma unroll
        for (int r = 0; r < 8; r++) {
            float x = rowsB[r * 128 + tid] * sc + sh;
            rowsB[r * 128 + tid] = x > 0.f ? x : 0.f;
        }
    }
    __syncthreads();
    if (tid < 56) {
        int r = tid / 7, jo = tid % 7;
        float a3 = o_b3[jo];
        #pragma unroll 8
        for (int k = 0; k < 128; k++) a3 += rowsB[r * 128 + k] * w3s[k * 7 + jo];
        out[(r0 + r) * 7 + jo] = a3;
    }
}

extern "C" void kernel_launch(void* const* d_in, const int* in_sizes, int n_in,
                              void* d_out, int out_size, void* d_ws, size_t ws_size,
                              hipStream_t stream) {
    const float* noise = (const float*)d_in[0];
    const int* tsteps = (const int*)d_in[1];
    const float* pcs = (const float*)d_in[2];
    const int* bl = (const int*)d_in[4];
    const float* pe_w = (const float*)d_in[5];
    const float* pe_b = (const float*)d_in[6];
    const float* t_w1 = (const float*)d_in[7];
    const float* t_b1 = (const float*)d_in[8];
    const float* t_w2 = (const float*)d_in[9];
    const float* t_b2 = (const float*)d_in[10];
    const float* pfc_w = (const float*)d_in[11];
    const float* pfc_b = (const float*)d_in[12];
    const float* o_w1 = (const float*)d_in[13];
    const float* o_b1 = (const float*)d_in[14];
    const float* bn1_g = (const float*)d_in[15];
    const float* bn1_b = (const float*)d_in[16];
    const float* o_w2 = (const float*)d_in[17];
    const float* o_b2 = (const float*)d_in[18];
    const float* bn2_g = (const float*)d_in[19];
    const float* bn2_b = (const float*)d_in[20];
    const float* o_w3 = (const float*)d_in[21];
    const float* o_b3 = (const float*)d_in[22];

    float* ws = (float*)d_ws;
    float* h1     = ws + 0;        // 16384
    float* WM     = ws + 16384;    // 664*256 -> 186368
    float* g1     = ws + 186368;   // 640*256 -> 350208
    float* tg     = ws + 350208;   // 32*256  -> 358400
    float* stats1 = ws + 358400;   // 512
    float* stats2 = ws + 358912;   // 256
    int*   cnts   = (int*)(ws + 359168); // 8 ints

    hipMemsetAsync(stats1, 0, (512 + 256 + 8) * sizeof(float), stream);
    kF<<<NBLK, 256, 0, stream>>>(noise, tsteps, pcs, bl, pe_w, pe_b,
                                 t_w1, t_b1, t_w2, t_b2, pfc_w, pfc_b,
                                 o_w1, o_b1, bn1_g, bn1_b, o_w2, o_b2,
                                 bn2_g, bn2_b, o_w3, o_b3,
                                 h1, WM, g1, tg, stats1, stats2, cnts,
                                 (float*)d_out);
}

// Round 11
// 146.859 us; speedup vs baseline: 1.6186x; 1.6186x over previous
//
#include <hip/hip_runtime.h>
#include <math.h>

#define NF 147
#define NBP 152   // padded nb row stride (147 nerf + rms at 148..150)

// ---------------------------------------------------------------------------
// k1 (455 blocks x 256): all cold-input streams in parallel.
//   0..127   h1 = silu(e @ t_w1 + t_b1)     (32 b x 4 j-quarters, k-split 2)
//   128..293 WM = concat(t_w2|pfc_w|pe_w|pe_b+pfc_b|t_b2) @ o_w1
//            (4 rows/block, LDS-staged src, float4, 4-way k-split)
//   294..453 geometry: pcs stage -> segment means -> quat -> rms; nerf -> nb
//            (4 segments/block; writes nb[s][0..146], rms at nb[s][148..150])
//   454      zero stats[768] + 2 barrier counters
// ---------------------------------------------------------------------------
__global__ __launch_bounds__(256) void k1(
    const float* __restrict__ noise, const int* __restrict__ tsteps,
    const float* __restrict__ pcs, const int* __restrict__ bl,
    const float* __restrict__ t_w1, const float* __restrict__ t_b1,
    const float* __restrict__ t_w2, const float* __restrict__ t_b2,
    const float* __restrict__ pe_w, const float* __restrict__ pe_b,
    const float* __restrict__ pfc_w, const float* __restrict__ pfc_b,
    const float* __restrict__ o_w1,
    float* __restrict__ h1, float* __restrict__ WM, float* __restrict__ nb,
    int* __restrict__ statsz)
{
    __shared__ float shm[6144];   // 24 KB
    __shared__ float np7s[4][8];
    __shared__ float wsum[4][3];
    __shared__ float rms[4][3];
    int blk = blockIdx.x, tid = threadIdx.x;

    if (blk < 128) {
        int b = blk >> 2, jq = blk & 3;
        float tf = (float)tsteps[b];
        float f = expf(-9.210340371976184f * (float)tid * (1.f / 256.f));
        float sn, cs;
        sincosf(tf * f, &sn, &cs);
        shm[tid] = cs; shm[256 + tid] = sn;          // e[512]
        __syncthreads();
        int jj = tid & 127, j = jq * 128 + jj;
        int ks = tid >> 7, k0 = ks << 8;
        float acc = 0.f;
        #pragma unroll 8
        for (int k = k0; k < k0 + 256; k++) acc += shm[k] * t_w1[k * 512 + j];
        shm[512 + ks * 128 + jj] = acc;
        __syncthreads();
        if (tid < 128) {
            float v = shm[512 + tid] + shm[640 + tid] + t_b1[jq * 128 + tid];
            h1[b * 512 + jq * 128 + tid] = v / (1.f + expf(-v));
        }
    } else if (blk < 294) {
        int m = blk - 128, r4 = m * 4;
        float* srcs = shm;          // [4][512]
        float* red  = shm + 2048;   // [4][4][256]
        #pragma unroll
        for (int q = 0; q < 2; q++) {
            int idx = tid + q * 256;          // 0..511 float4 units
            int row = idx >> 7;
            int off4 = (idx & 127) << 2;
            int kr = r4 + row;
            float4 v;
            if (kr < 512)      v = *(const float4*)&t_w2[(size_t)kr * 512 + off4];
            else if (kr < 659) v = *(const float4*)&pfc_w[(size_t)(kr - 512) * 512 + off4];
            else if (kr < 662) v = *(const float4*)&pe_w[(size_t)(kr - 659) * 512 + off4];
            else if (kr == 662) {
                float4 a = *(const float4*)&pe_b[off4];
                float4 bq = *(const float4*)&pfc_b[off4];
                v.x = a.x + bq.x; v.y = a.y + bq.y; v.z = a.z + bq.z; v.w = a.w + bq.w;
            } else v = *(const float4*)&t_b2[off4];
            *(float4*)&srcs[row * 512 + off4] = v;
        }
        __syncthreads();
        int ks = tid >> 6, c4 = (tid & 63) << 2;
        float4 acc[4];
        #pragma unroll
        for (int i = 0; i < 4; i++) acc[i] = make_float4(0.f, 0.f, 0.f, 0.f);
        int j0 = ks * 128;
        #pragma unroll 4
        for (int jj = 0; jj < 128; jj++) {
            int j = j0 + jj;
            float4 w = *(const float4*)&o_w1[j * 256 + c4];
            #pragma unroll
            for (int i = 0; i < 4; i++) {
                float s = srcs[i * 512 + j];
                acc[i].x += s * w.x; acc[i].y += s * w.y;
                acc[i].z += s * w.z; acc[i].w += s * w.w;
            }
        }
        #pragma unroll
        for (int i = 0; i < 4; i++) *(float4*)&red[(ks * 4 + i) * 256 + c4] = acc[i];
        __syncthreads();
        #pragma unroll
        for (int t = 0; t < 4; t++) {
            int o = tid + t * 256;            // 0..1023
            int i = o >> 8, c = o & 255;
            WM[(size_t)(r4 + i) * 256 + c] = red[i * 256 + c] + red[(4 + i) * 256 + c]
                                           + red[(8 + i) * 256 + c] + red[(12 + i) * 256 + c];
        }
    } else if (blk < 454) {
        int blkg = blk - 294;
        int s0 = blkg * 4;
        {
            const float4* p4 = (const float4*)(pcs + (size_t)blkg * 3000);
            #pragma unroll
            for (int i = 0; i < 3; i++) {
                int idx = tid + i * 256;
                if (idx < 750) *(float4*)&shm[idx * 4] = p4[idx];
            }
        }
        if (tid < 28) np7s[tid / 7][tid % 7] = noise[s0 * 7 + tid];
        __syncthreads();
        int w = tid >> 6, lane = tid & 63;
        {
            float sx = 0.f, sy = 0.f, sz = 0.f;
            const float* base = shm + w * 750;
            #pragma unroll
            for (int it = 0; it < 4; it++) {
                int q = lane + it * 64;
                if (q < 250) {
                    sx += base[q * 3 + 0];
                    sy += base[q * 3 + 1];
                    sz += base[q * 3 + 2];
                }
            }
            for (int off = 32; off >= 1; off >>= 1) {
                sx += __shfl_down(sx, off, 64);
                sy += __shfl_down(sy, off, 64);
                sz += __shfl_down(sz, off, 64);
            }
            if (lane == 0) { wsum[w][0] = sx; wsum[w][1] = sy; wsum[w][2] = sz; }
        }
        __syncthreads();
        if (tid < 4) {
            float inv = 1.f / (float)bl[s0 + tid];
            float mx = wsum[tid][0] * inv, my = wsum[tid][1] * inv, mz = wsum[tid][2] * inv;
            float qw = np7s[tid][3], qx = np7s[tid][4], qy = np7s[tid][5], qz = np7s[tid][6];
            float qn = rsqrtf(qw * qw + qx * qx + qy * qy + qz * qz);
            qw *= qn; qx *= qn; qy *= qn; qz *= qn;
            float tx = 2.f * (qy * mz - qz * my);
            float ty = 2.f * (qz * mx - qx * mz);
            float tz = 2.f * (qx * my - qy * mx);
            float r0 = mx + qw * tx + (qy * tz - qz * ty) + np7s[tid][0];
            float r1 = my + qw * ty + (qz * tx - qx * tz) + np7s[tid][1];
            float r2 = mz + qw * tz + (qx * ty - qy * tx) + np7s[tid][2];
            nb[(size_t)(s0 + tid) * NBP + 148] = r0;
            nb[(size_t)(s0 + tid) * NBP + 149] = r1;
            nb[(size_t)(s0 + tid) * NBP + 150] = r2;
        }
        for (int u = tid; u < 4 * NF; u += 256) {
            int r = u / NF, f = u % NF;
            float v;
            if (f < 7) v = np7s[r][f];
            else {
                int j = f - 7;
                int fi = j / 14, x = j % 14;
                float band = (float)(1 << fi);
                v = (x < 7) ? sinf(np7s[r][x] * band) : cosf(np7s[r][x - 7] * band);
            }
            nb[(size_t)(s0 + r) * NBP + f] = v;
        }
    } else {
        for (int z = tid; z < 772; z += 256) statsz[z] = 0;
    }
}

// ---------------------------------------------------------------------------
// k2 (288 blocks x 256): pure GEMV phase.
//   0..159   g1[s][c] = nb[s]·WM[512+f] + rms[s]·WM[659+d] + WM[662]  (k=151,
//            4-row register blocking; nb rows float4-staged to LDS)
//   160..287 tg[b][c-quarter] = h1[b,:]·WM[0:512,c] + WM[663,c] + o_b1[c]
//            (32 b x 4 c-quarters, 4-way k-split)
// ---------------------------------------------------------------------------
__global__ __launch_bounds__(256) void k2(
    const float* __restrict__ o_b1,
    const float* __restrict__ h1, const float* __restrict__ WM,
    const float* __restrict__ nb,
    float* __restrict__ g1, float* __restrict__ tg)
{
    __shared__ float shm[1024];
    int blk = blockIdx.x, tid = threadIdx.x;

    if (blk < 160) {
        int s0 = blk * 4;
        if (tid < 152) {   // 4 rows x 38 float4 = 152 units = 608 floats
            ((float4*)shm)[tid] = ((const float4*)(nb + (size_t)s0 * NBP))[tid];
        }
        __syncthreads();
        int c = tid;
        float b0 = WM[662 * 256 + c];
        float a0 = b0, a1 = b0, a2 = b0, a3 = b0;
        #pragma unroll 7
        for (int f = 0; f < NF; f++) {
            float wv = WM[(512 + f) * 256 + c];
            a0 += shm[f] * wv;
            a1 += shm[NBP + f] * wv;
            a2 += shm[2 * NBP + f] * wv;
            a3 += shm[3 * NBP + f] * wv;
        }
        #pragma unroll
        for (int d = 0; d < 3; d++) {
            float wv = WM[(659 + d) * 256 + c];
            a0 += shm[148 + d] * wv;
            a1 += shm[NBP + 148 + d] * wv;
            a2 += shm[2 * NBP + 148 + d] * wv;
            a3 += shm[3 * NBP + 148 + d] * wv;
        }
        g1[(s0 + 0) * 256 + c] = a0;
        g1[(s0 + 1) * 256 + c] = a1;
        g1[(s0 + 2) * 256 + c] = a2;
        g1[(s0 + 3) * 256 + c] = a3;
    } else {
        int q = blk - 160;
        int b = q >> 2, cq = q & 3;           // 32 batches x 4 col-quarters
        shm[tid] = h1[b * 512 + tid];
        shm[256 + tid] = h1[b * 512 + 256 + tid];
        __syncthreads();
        int ks = tid >> 6, cc = tid & 63;     // 4-way k-split, 64 cols
        int c = cq * 64 + cc;
        int k0 = ks * 128;
        float acc = 0.f;
        #pragma unroll 8
        for (int k = k0; k < k0 + 128; k++) acc += shm[k] * WM[k * 256 + c];
        shm[512 + ks * 64 + cc] = acc;
        __syncthreads();
        if (tid < 64) {
            int c2 = cq * 64 + tid;
            tg[b * 256 + c2] = shm[512 + tid] + shm[576 + tid] + shm[640 + tid]
                             + shm[704 + tid] + WM[663 * 256 + c2] + o_b1[c2];
        }
    }
}

// ---------------------------------------------------------------------------
// kCD: 80 blocks x 128 threads, co-resident (verbatim from R9 — validated).
// ---------------------------------------------------------------------------
__global__ __launch_bounds__(128) void kCD(
    const float* __restrict__ g1, const float* __restrict__ tg,
    float* __restrict__ stats1,
    const float* __restrict__ bn1_g, const float* __restrict__ bn1_b,
    const float* __restrict__ o_w2, const float* __restrict__ o_b2,
    const float* __restrict__ bn2_g, const float* __restrict__ bn2_b,
    const float* __restrict__ o_w3, const float* __restrict__ o_b3,
    float* __restrict__ stats2, int* __restrict__ cntA, int* __restrict__ cntB,
    float* __restrict__ out)
{
    int blk = blockIdx.x, tid = threadIdx.x;
    int r0 = blk * 8;
    __shared__ float rows[8][256];
    __shared__ float scale[256], shift[256];
    __shared__ float rowsB[8][128];
    __shared__ float w3[128 * 7];

    #pragma unroll
    for (int w = 0; w < 4; w++) {
        int idx4 = (tid + w * 128) << 2;
        int r = idx4 >> 8, c = idx4 & 255;
        int s = r0 + r;
        float4 gv = *(const float4*)&g1[s * 256 + c];
        float4 tv = *(const float4*)&tg[(s / 20) * 256 + c];
        gv.x += tv.x; gv.y += tv.y; gv.z += tv.z; gv.w += tv.w;
        *(float4*)&rows[r][c] = gv;
    }
    for (int i = tid; i < 128 * 7; i += 128) w3[i] = o_w3[i];
    __syncthreads();
    for (int c = tid; c < 256; c += 128) {
        float sm = 0.f, ss = 0.f;
        #pragma unroll
        for (int r = 0; r < 8; r++) { float x = rows[r][c]; sm += x; ss += x * x; }
        atomicAdd(&stats1[c], sm);
        atomicAdd(&stats1[256 + c], ss);
    }

    __syncthreads();
    if (tid == 0) {
        __threadfence();
        atomicAdd(cntA, 1);
        while (atomicAdd(cntA, 0) < 80) { }
        __threadfence();
    }
    __syncthreads();

    for (int c = tid; c < 256; c += 128) {
        float m = stats1[c] * (1.f / 640.f);
        float v = stats1[256 + c] * (1.f / 640.f) - m * m;
        float sc = rsqrtf(v + 1e-5f) * bn1_g[c];
        scale[c] = sc;
        shift[c] = bn1_b[c] - m * sc;
    }
    __syncthreads();
    for (int i = tid; i < 2048; i += 128) {
        int r = i >> 8, c = i & 255;
        float x = rows[r][c] * scale[c] + shift[c];
        rows[r][c] = x > 0.f ? x : 0.f;
    }
    __syncthreads();

    float acc[8];
    float bb = o_b2[tid];
    #pragma unroll
    for (int r = 0; r < 8; r++) acc[r] = bb;
    #pragma unroll 8
    for (int k = 0; k < 256; k++) {
        float w = o_w2[k * 128 + tid];
        #pragma unroll
        for (int r = 0; r < 8; r++) acc[r] += rows[r][k] * w;
    }
    float sm = 0.f, ss = 0.f;
    #pragma unroll
    for (int r = 0; r < 8; r++) { sm += acc[r]; ss += acc[r] * acc[r]; }
    atomicAdd(&stats2[tid], sm);
    atomicAdd(&stats2[128 + tid], ss);

    __syncthreads();
    if (tid == 0) {
        __threadfence();
        atomicAdd(cntB, 1);
        while (atomicAdd(cntB, 0) < 80) { }
        __threadfence();
    }
    __syncthreads();

    {
        float m = stats2[tid] * (1.f / 640.f);
        float v = stats2[128 + tid] * (1.f / 640.f) - m * m;
        float sc = rsqrtf(v + 1e-5f) * bn2_g[tid];
        float sh2 = bn2_b[tid] - m * sc;
        #pragma unroll
        for (int r = 0; r < 8; r++) {
            float x = acc[r] * sc + sh2;
            rowsB[r][tid] = x > 0.f ? x : 0.f;
        }
    }
    __syncthreads();
    if (tid < 56) {
        int r = tid / 7, j = tid % 7;
        float a3 = o_b3[j];
        #pragma unroll 8
        for (int k = 0; k < 128; k++) a3 += rowsB[r][k] * w3[k * 7 + j];
        out[(r0 + r) * 7 + j] = a3;
    }
}

extern "C" void kernel_launch(void* const* d_in, const int* in_sizes, int n_in,
                              void* d_out, int out_size, void* d_ws, size_t ws_size,
                              hipStream_t stream) {
    const float* noise = (const float*)d_in[0];
    const int* tsteps = (const int*)d_in[1];
    const float* pcs = (const float*)d_in[2];
    const int* bl = (const int*)d_in[4];
    const float* pe_w = (const float*)d_in[5];
    const float* pe_b = (const float*)d_in[6];
    const float* t_w1 = (const float*)d_in[7];
    const float* t_b1 = (const float*)d_in[8];
    const float* t_w2 = (const float*)d_in[9];
    const float* t_b2 = (const float*)d_in[10];
    const float* pfc_w = (const float*)d_in[11];
    const float* pfc_b = (const float*)d_in[12];
    const float* o_w1 = (const float*)d_in[13];
    const float* o_b1 = (const float*)d_in[14];
    const float* bn1_g = (const float*)d_in[15];
    const float* bn1_b = (const float*)d_in[16];
    const float* o_w2 = (const float*)d_in[17];
    const float* o_b2 = (const float*)d_in[18];
    const float* bn2_g = (const float*)d_in[19];
    const float* bn2_b = (const float*)d_in[20];
    const float* o_w3 = (const float*)d_in[21];
    const float* o_b3 = (const float*)d_in[22];

    float* ws = (float*)d_ws;
    float* h1    = ws + 0;        // 16384
    float* WM    = ws + 16384;    // 664*256 -> 186368
    float* nb    = ws + 186368;   // 640*152 = 97280 -> 283648
    float* g1    = ws + 283648;   // 640*256 -> 447488
    float* tg    = ws + 447488;   // 8192   -> 455680
    float* stats = ws + 455680;   // 768
    int*   cnt   = (int*)(ws + 456448); // 2 counters (zeroed by k1 blk 454)

    k1<<<455, 256, 0, stream>>>(noise, tsteps, pcs, bl, t_w1, t_b1, t_w2, t_b2,
                                pe_w, pe_b, pfc_w, pfc_b, o_w1,
                                h1, WM, nb, (int*)stats);
    k2<<<288, 256, 0, stream>>>(o_b1, h1, WM, nb, g1, tg);
    kCD<<<80, 128, 0, stream>>>(g1, tg, stats, bn1_g, bn1_b, o_w2, o_b2,
                                bn2_g, bn2_b, o_w3, o_b3,
                                stats + 512, cnt, cnt + 1, (float*)d_out);
}